// Round 13
// baseline (888.100 us; speedup 1.0000x reference)
//
#include <hip/hip_runtime.h>
#include <hip/hip_bf16.h>

#define GNUM 64
#define BN_EPS 1e-5f

typedef unsigned short u16;
typedef unsigned int u32;
typedef __attribute__((ext_vector_type(8))) short short8;
typedef __attribute__((ext_vector_type(4))) float f32x4;

__device__ inline float bflo(u32 u) { union { u32 i; float f; } v; v.i = u << 16; return v.f; }
__device__ inline float bfhi(u32 u) { union { u32 i; float f; } v; v.i = u & 0xFFFF0000u; return v.f; }
__device__ inline u16 f2bf(float f) {
    union { float f; u32 i; } v; v.f = f;
    u32 x = v.i;
    return (u16)((x + 0x7FFFu + ((x >> 16) & 1u)) >> 16);  // RNE
}
__device__ inline u32 pack2(float a, float b) { return (u32)f2bf(a) | ((u32)f2bf(b) << 16); }
__device__ inline void acc8(float* a, uint4 v) {
    a[0] += bflo(v.x); a[1] += bfhi(v.x); a[2] += bflo(v.y); a[3] += bfhi(v.y);
    a[4] += bflo(v.z); a[5] += bfhi(v.z); a[6] += bflo(v.w); a[7] += bfhi(v.w);
}

// ---------------- zero-init ----------------
__global__ void zero_f(float* __restrict__ p, int n) {
    int i = blockIdx.x * 256 + threadIdx.x;
    if (i < n) p[i] = 0.f;
}
__global__ void zero_i(int* __restrict__ p, int n) {
    int i = blockIdx.x * 256 + threadIdx.x;
    if (i < n) p[i] = 0;
}

// ---------------- CSR build ----------------
__global__ void deg_kernel(const int* __restrict__ dst, int* __restrict__ deg, int E) {
    int e = blockIdx.x * 256 + threadIdx.x;
    if (e < E) atomicAdd(&deg[dst[e]], 1);
}

__global__ void scan_block(const int* __restrict__ deg, int* __restrict__ part,
                           int* __restrict__ bsum, int n) {
    __shared__ int tmp[256];
    int i = blockIdx.x * 256 + threadIdx.x;
    int v = (i < n) ? deg[i] : 0;
    tmp[threadIdx.x] = v;
    __syncthreads();
    for (int off = 1; off < 256; off <<= 1) {
        int x = 0;
        if (threadIdx.x >= off) x = tmp[threadIdx.x - off];
        __syncthreads();
        tmp[threadIdx.x] += x;
        __syncthreads();
    }
    if (i < n) part[i] = tmp[threadIdx.x];
    if (threadIdx.x == 255) bsum[blockIdx.x] = tmp[255];
}

__global__ void scan_bsum(int* __restrict__ bsum, int nb) {
    __shared__ int tmp[256];
    int v = (threadIdx.x < nb) ? bsum[threadIdx.x] : 0;
    tmp[threadIdx.x] = v;
    __syncthreads();
    for (int off = 1; off < 256; off <<= 1) {
        int x = 0;
        if (threadIdx.x >= off) x = tmp[threadIdx.x - off];
        __syncthreads();
        tmp[threadIdx.x] += x;
        __syncthreads();
    }
    if (threadIdx.x < nb) bsum[threadIdx.x] = tmp[threadIdx.x];
}

__global__ void scan_fix(const int* __restrict__ part, const int* __restrict__ bsum,
                         int* __restrict__ offs, int* __restrict__ cursor, int n) {
    int i = blockIdx.x * 256 + threadIdx.x;
    if (i >= n) return;
    int add = (blockIdx.x > 0) ? bsum[blockIdx.x - 1] : 0;
    int incl = part[i] + add;
    offs[i + 1] = incl;
    cursor[i + 1] = incl;
    if (i == 0) { offs[0] = 0; cursor[0] = 0; }
}

__global__ void fill_kernel(const int* __restrict__ src, const int* __restrict__ dst,
                            int* __restrict__ cursor, int* __restrict__ eidx, int E) {
    int e = blockIdx.x * 256 + threadIdx.x;
    if (e >= E) return;
    int d = dst[e];
    int p = atomicAdd(&cursor[d], 1);
    eidx[p] = src[e];
}

__global__ void cnt_kernel(const int* __restrict__ batch, float* __restrict__ cnt, int Nn) {
    int tid = blockIdx.x * blockDim.x + threadIdx.x;
    int s = tid * 64;
    if (s >= Nn) return;
    int e = min(s + 64, Nn);
    int cur = batch[s]; int run = 0;
    for (int r = s; r < e; ++r) {
        int b = batch[r];
        if (b != cur) { atomicAdd(&cnt[cur], (float)run); cur = b; run = 0; }
        run++;
    }
    atomicAdd(&cnt[cur], (float)run);
}

// ---------------- x fp32 -> bf16 ----------------
__global__ void cvt_x(const float* __restrict__ x, u16* __restrict__ xb, int total4) {
    int i = blockIdx.x * 256 + threadIdx.x;
    if (i >= total4) return;
    float4 v = *(const float4*)&x[i * 4];
    uint2 o;
    o.x = pack2(v.x, v.y);
    o.y = pack2(v.z, v.w);
    *(uint2*)&xb[i * 4] = o;
}

// ---------------- weight -> MFMA-fragment-ordered bf16 ----------------
// Wp short8 index o = ((t*(K/32) + kc)*8 + jf)*64 + l; element e:
//   k = kc*32 + (l>>4)*8 + e,  col = t*128 + jf*16 + (l&15)
template<int K>
__global__ void transw_frag(const float* __restrict__ W, u16* __restrict__ Wp) {
    int o = blockIdx.x * 256 + threadIdx.x;
    if (o >= K * 32) return;
    int l = o & 63;
    int q1 = o >> 6;
    int jf = q1 & 7;
    int q2 = q1 >> 3;
    const int KC = K / 32;
    int kc = q2 & (KC - 1);
    int t = q2 / KC;
    int kbase = kc * 32 + ((l >> 4) << 3);
    int col = t * 128 + jf * 16 + (l & 15);
#pragma unroll
    for (int e = 0; e < 8; ++e)
        Wp[(size_t)o * 8 + e] = f2bf(W[(size_t)(kbase + e) * 256 + col]);
}

// ---------------- fused GIN layer: gather + MLP ------------------------------------
// z[n] = h[n] + sum_{j->n} h[src_j];  out = (relu(z@W1+b1))@W2 + b2;  stats += col sums.
// Block = 64 rows x full 256 cols; 4 waves, wave w owns output cols [w*64, w*64+64).
// Phase 0: CSR gather (agg3 logic) for own 64 rows -> As in frag-major layout.
// Phase 1: GEMM1 (register-dbuf B from L2), ReLU.
// Phase 2: h1 -> Hs in A-frag layout. Phase 3: GEMM2. Epilogue: v5.1 transpose + stats.
template<int K1>
__global__ __launch_bounds__(256, 2)
void gin_fused(const u16* __restrict__ Hin, const int* __restrict__ offs,
               const int* __restrict__ eidx,
               const u16* __restrict__ W1p, const float* __restrict__ b1,
               const u16* __restrict__ W2p, const float* __restrict__ b2,
               u16* __restrict__ Cout, float* __restrict__ stats, int M) {
    constexpr int KC1 = K1 / 32;
    __shared__ u16 As[64 * K1];         // z tile, frag-major
    __shared__ u16 Hs[64 * 256];        // h1 tile, A-frag layout for GEMM2
    __shared__ u16 tbuf[4608];          // 4 waves x 16 rows x 72 u16
    __shared__ float cs[256];
    int t = threadIdx.x;
    int lane = t & 63, wave = t >> 6;
    int m0 = blockIdx.x * 64;
    int lm = lane & 15, q = lane >> 4;

    // --- phase 0: gather + stage. Wave w handles local rows w*16..w*16+15. ---
    {
        const int CH = K1 / 8;          // 16B chunks per row (16 or 32)
        const int G = 64 / CH;          // edge groups per wave (4 or 2)
        int cc = lane & (CH - 1);
        int g = lane / CH;
        const u16* hp = Hin + cc * 8;
        for (int rr = 0; rr < 16; ++rr) {
            int n = m0 + wave * 16 + rr;
            if (n >= M) n = M - 1;
            float a[8] = {0.f, 0.f, 0.f, 0.f, 0.f, 0.f, 0.f, 0.f};
            if (g == 0) acc8(a, *(const uint4*)&hp[(size_t)n * K1]);  // self
            int j1 = offs[n + 1];
            int j = offs[n] + g;
            for (; j + 3 * G < j1; j += 4 * G) {
                int s0 = eidx[j], s1 = eidx[j + G], s2 = eidx[j + 2 * G], s3 = eidx[j + 3 * G];
                uint4 v0 = *(const uint4*)&hp[(size_t)s0 * K1];
                uint4 v1 = *(const uint4*)&hp[(size_t)s1 * K1];
                uint4 v2 = *(const uint4*)&hp[(size_t)s2 * K1];
                uint4 v3 = *(const uint4*)&hp[(size_t)s3 * K1];
                acc8(a, v0); acc8(a, v1); acc8(a, v2); acc8(a, v3);
            }
            for (; j < j1; j += G) {
                uint4 v = *(const uint4*)&hp[(size_t)eidx[j] * K1];
                acc8(a, v);
            }
#pragma unroll
            for (int off = 32; off >= CH; off >>= 1)
#pragma unroll
                for (int e = 0; e < 8; ++e) a[e] += __shfl_down(a[e], off, 64);
            if (g == 0) {
                int kc = cc >> 2, qq = cc & 3;
                uint4 o;
                o.x = pack2(a[0], a[1]); o.y = pack2(a[2], a[3]);
                o.z = pack2(a[4], a[5]); o.w = pack2(a[6], a[7]);
                *(uint4*)&As[((wave * KC1 + kc) * 64 + rr + (qq << 4)) * 8] = o;
            }
        }
    }
    __syncthreads();

    f32x4 acc[4][4];
#pragma unroll
    for (int i = 0; i < 4; ++i)
#pragma unroll
        for (int j = 0; j < 4; ++j) acc[i][j] = (f32x4)0.0f;

    // --- phase 1: GEMM1. wave w: cols w*64.. ---
    {
        const u16* bbase = W1p + ((((size_t)(wave >> 1) * KC1) * 8 + ((wave & 1) << 2)) * 64 + lane) * 8;
        short8 a0[4], a1[4], b0[4], b1r[4];
#pragma unroll
        for (int i = 0; i < 4; ++i) a0[i] = *(const short8*)&As[(i * KC1) * 512 + lane * 8];
#pragma unroll
        for (int j = 0; j < 4; ++j) b0[j] = *(const short8*)(bbase + j * 512);
#pragma unroll
        for (int kc = 0; kc < KC1; ++kc) {
            short8* ac = (kc & 1) ? a1 : a0;
            short8* bc = (kc & 1) ? b1r : b0;
            short8* an = (kc & 1) ? a0 : a1;
            short8* bn = (kc & 1) ? b0 : b1r;
            if (kc + 1 < KC1) {
#pragma unroll
                for (int i = 0; i < 4; ++i)
                    an[i] = *(const short8*)&As[(i * KC1 + kc + 1) * 512 + lane * 8];
#pragma unroll
                for (int j = 0; j < 4; ++j)
                    bn[j] = *(const short8*)(bbase + (size_t)(kc + 1) * 4096 + j * 512);
            }
#pragma unroll
            for (int i = 0; i < 4; ++i)
#pragma unroll
                for (int j = 0; j < 4; ++j)
                    acc[i][j] = __builtin_amdgcn_mfma_f32_16x16x32_bf16(ac[i], bc[j], acc[i][j], 0, 0, 0);
        }
    }

    // --- phase 2: h1 = relu(acc + b1) -> Hs in A-frag layout ---
    // C/D: row = i*16 + q*4 + r, col = w*64 + j*16 + lm.
    // A-frag: Hs[((mf*8 + kc)*64 + r15 + qq*16)*8 + e],
    //   mf=i, r15=q*4+r, kc=w*2+(j>>1), qq=(j&1)*2+(lm>>3), e=lm&7.
    {
#pragma unroll
        for (int j = 0; j < 4; ++j) {
            float bv = b1[wave * 64 + j * 16 + lm];
            int kc = wave * 2 + (j >> 1);
            int qq = ((j & 1) << 1) + (lm >> 3);
            int e = lm & 7;
#pragma unroll
            for (int i = 0; i < 4; ++i) {
#pragma unroll
                for (int r = 0; r < 4; ++r) {
                    float v = fmaxf(acc[i][j][r] + bv, 0.f);
                    Hs[(((i * 8 + kc) * 64) + (q * 4 + r) + qq * 16) * 8 + e] = f2bf(v);
                }
            }
        }
    }
    __syncthreads();

    // --- phase 3: GEMM2 (K = 256, A from Hs) ---
#pragma unroll
    for (int i = 0; i < 4; ++i)
#pragma unroll
        for (int j = 0; j < 4; ++j) acc[i][j] = (f32x4)0.0f;
    {
        const u16* bbase = W2p + ((((size_t)(wave >> 1) * 8) * 8 + ((wave & 1) << 2)) * 64 + lane) * 8;
        short8 a0[4], a1[4], b0[4], b1r[4];
#pragma unroll
        for (int i = 0; i < 4; ++i) a0[i] = *(const short8*)&Hs[(i * 8) * 512 + lane * 8];
#pragma unroll
        for (int j = 0; j < 4; ++j) b0[j] = *(const short8*)(bbase + j * 512);
#pragma unroll
        for (int kc = 0; kc < 8; ++kc) {
            short8* ac = (kc & 1) ? a1 : a0;
            short8* bc = (kc & 1) ? b1r : b0;
            short8* an = (kc & 1) ? a0 : a1;
            short8* bn = (kc & 1) ? b0 : b1r;
            if (kc + 1 < 8) {
#pragma unroll
                for (int i = 0; i < 4; ++i)
                    an[i] = *(const short8*)&Hs[(i * 8 + kc + 1) * 512 + lane * 8];
#pragma unroll
                for (int j = 0; j < 4; ++j)
                    bn[j] = *(const short8*)(bbase + (size_t)(kc + 1) * 4096 + j * 512);
            }
#pragma unroll
            for (int i = 0; i < 4; ++i)
#pragma unroll
                for (int j = 0; j < 4; ++j)
                    acc[i][j] = __builtin_amdgcn_mfma_f32_16x16x32_bf16(ac[i], bc[j], acc[i][j], 0, 0, 0);
        }
    }

    // --- epilogue: v5.1-proven transpose; stats always ---
    float bv2[4], s_sum[4], s_sq[4];
#pragma unroll
    for (int j = 0; j < 4; ++j) {
        bv2[j] = b2[wave * 64 + j * 16 + lm];
        s_sum[j] = 0.f; s_sq[j] = 0.f;
    }
#pragma unroll
    for (int i = 0; i < 4; ++i) {
#pragma unroll
        for (int j = 0; j < 4; ++j) {
#pragma unroll
            for (int r = 0; r < 4; ++r) {
                int row = m0 + i * 16 + q * 4 + r;
                float v = acc[i][j][r] + bv2[j];
                if (row < M) { s_sum[j] += v; s_sq[j] = fmaf(v, v, s_sq[j]); }
                tbuf[wave * 1152 + (q * 4 + r) * 72 + j * 16 + lm] = f2bf(v);
            }
        }
        __syncthreads();
        int rl = lane >> 2, seg = lane & 3;
        uint4 w0 = *(const uint4*)&tbuf[wave * 1152 + rl * 72 + seg * 16];
        uint4 w1 = *(const uint4*)&tbuf[wave * 1152 + rl * 72 + seg * 16 + 8];
        int rowg = m0 + i * 16 + rl;
        if (rowg < M) {
            u16* cp = Cout + (size_t)rowg * 256 + wave * 64 + seg * 16;
            *(uint4*)cp = w0;
            *(uint4*)(cp + 8) = w1;
        }
        __syncthreads();
    }

    cs[t] = 0.f;
    __syncthreads();
#pragma unroll
    for (int j = 0; j < 4; ++j)
        atomicAdd(&cs[wave * 64 + j * 16 + lm], s_sum[j]);
    __syncthreads();
    atomicAdd(&stats[t], cs[t]);
    __syncthreads();
    cs[t] = 0.f;
    __syncthreads();
#pragma unroll
    for (int j = 0; j < 4; ++j)
        atomicAdd(&cs[wave * 64 + j * 16 + lm], s_sq[j]);
    __syncthreads();
    atomicAdd(&stats[256 + t], cs[t]);
}

// ---------------- BN apply + ReLU + segmented max/sum pool ----------------
__global__ __launch_bounds__(256)
void bn_pool(const u16* __restrict__ Z, const float* __restrict__ stats,
             const float* __restrict__ gamma, const float* __restrict__ beta,
             const int* __restrict__ batch, u16* __restrict__ H,
             float* __restrict__ pool_max, float* __restrict__ pool_sum, int Nn) {
    int col = threadIdx.x;
    int r0 = blockIdx.x * 64;
    if (r0 >= Nn) return;
    float mu = stats[col] / (float)Nn;
    float var = stats[256 + col] / (float)Nn - mu * mu;
    float scale = gamma[col] * rsqrtf(var + BN_EPS);
    float shift = beta[col] - mu * scale;
    int rend = min(r0 + 64, Nn);
    int cur = batch[r0];
    float rmax = 0.f, rsum = 0.f;
    for (int r = r0; r < rend; ++r) {
        int bb = batch[r];
        if (bb != cur) {
            atomicMax((int*)&pool_max[cur * 256 + col], __float_as_int(rmax));
            atomicAdd(&pool_sum[cur * 256 + col], rsum);
            cur = bb; rmax = 0.f; rsum = 0.f;
        }
        float v = fmaf(bflo(Z[(size_t)r * 256 + col]), scale, shift);
        v = fmaxf(v, 0.f);  // >=0 so int atomicMax on float bits is valid
        H[(size_t)r * 256 + col] = f2bf(v);
        rmax = fmaxf(rmax, v); rsum += v;
    }
    atomicMax((int*)&pool_max[cur * 256 + col], __float_as_int(rmax));
    atomicAdd(&pool_sum[cur * 256 + col], rsum);
}

// ---------------- acc += concat(max, mean); reset pmax/psum/stats for next layer ----------------
__global__ void acc_update(float* __restrict__ pmax, float* __restrict__ psum,
                           const float* __restrict__ cnt, float* __restrict__ acc,
                           float* __restrict__ stats) {
    int i = blockIdx.x * 256 + threadIdx.x;  // GNUM*512 total
    int g = i >> 9, c = i & 511;
    float v;
    if (c < 256) {
        v = pmax[g * 256 + c];
        pmax[g * 256 + c] = 0.f;
    } else {
        int cc = c - 256;
        v = psum[g * 256 + cc] / fmaxf(cnt[g], 1.f);
        psum[g * 256 + cc] = 0.f;
    }
    acc[i] += v;
    if (i < 512) stats[i] = 0.f;
}

// ---------------- fused readout MLP (fp32): [64,512]->256->128->250 ----------------
__global__ __launch_bounds__(256)
void readout_kernel(const float* __restrict__ acc,
                    const float* __restrict__ w1, const float* __restrict__ b1,
                    const float* __restrict__ w2, const float* __restrict__ b2,
                    const float* __restrict__ w3, const float* __restrict__ b3,
                    float* __restrict__ out) {
    __shared__ float a[512], z1[256], z2[128];
    int g = blockIdx.x, t = threadIdx.x;
    a[t] = acc[g * 512 + t];
    a[t + 256] = acc[g * 512 + 256 + t];
    __syncthreads();
    float s = b1[t];
    for (int k = 0; k < 512; ++k) s = fmaf(a[k], w1[k * 256 + t], s);
    z1[t] = fmaxf(s, 0.f);
    __syncthreads();
    if (t < 128) {
        float s2 = b2[t];
        for (int k = 0; k < 256; ++k) s2 = fmaf(z1[k], w2[k * 128 + t], s2);
        z2[t] = fmaxf(s2, 0.f);
    }
    __syncthreads();
    if (t < 250) {
        float s3 = b3[t];
        for (int k = 0; k < 128; ++k) s3 = fmaf(z2[k], w3[k * 250 + t], s3);
        out[g * 250 + t] = s3;
    }
}

extern "C" void kernel_launch(void* const* d_in, const int* in_sizes, int n_in,
                              void* d_out, int out_size, void* d_ws, size_t ws_size,
                              hipStream_t stream) {
    const float* x     = (const float*)d_in[0];
    const int* ei      = (const int*)d_in[1];
    const int* batch   = (const int*)d_in[2];
    const float* w1a   = (const float*)d_in[3];
    const float* b1a   = (const float*)d_in[4];
    const float* w1b   = (const float*)d_in[5];
    const float* b1b   = (const float*)d_in[6];
    const float* W_in  = (const float*)d_in[7];
    const float* b_in  = (const float*)d_in[8];
    const float* W_out = (const float*)d_in[9];
    const float* b_out = (const float*)d_in[10];
    const float* gamma = (const float*)d_in[11];
    const float* beta  = (const float*)d_in[12];
    const float* l1w   = (const float*)d_in[13];
    const float* l1b   = (const float*)d_in[14];
    const float* l2w   = (const float*)d_in[15];
    const float* l2b   = (const float*)d_in[16];
    const float* l3w   = (const float*)d_in[17];
    const float* l3b   = (const float*)d_in[18];

    const int N = in_sizes[2];
    const int E = in_sizes[1] / 2;
    const int* srcv = ei;
    const int* dstv = ei + E;

    // ---- workspace layout (~82 MB) ----
    u16* B0 = (u16*)d_ws;                       // N*256 bf16 (z2 output, all layers)
    u16* B1 = B0 + (size_t)N * 256;             // N*256 bf16 (Xb only)
    u16* B2 = B1 + (size_t)N * 256;             // N*256 bf16 (post-BN H)
    u16* Xb = B1;                               // N*128 bf16
    u16* Wp = B2 + (size_t)N * 256;             // 32768 + 7*65536 u16 frag-ordered weights
    float* stats = (float*)(Wp + 32768 + 7 * 65536);  // 512
    float* pmax  = stats + 512;                 // 16384
    float* psum  = pmax + GNUM * 256;           // 16384
    float* acc   = psum + GNUM * 256;           // 32768
    float* cnt   = acc + GNUM * 512;            // 64
    int* deg    = (int*)(cnt + GNUM);           // N
    int* part   = deg + N;                      // N
    int* bsum   = part + N;                     // 256
    int* offs   = bsum + 256;                   // N+1
    int* cursor = offs + N + 1;                 // N+1
    int* eidx   = cursor + N + 1;               // E

    int nb256 = (N + 255) / 256;
    int nbM   = (N + 63) / 64;
    int nb64  = (N + 63) / 64;
    int eb    = (E + 255) / 256;
    const int FTOT = 512 + GNUM * 256 * 2 + GNUM * 512 + GNUM;  // 66112

    // --- init + CSR build + per-graph counts ---
    zero_i<<<nb256, 256, 0, stream>>>(deg, N);
    zero_f<<<(FTOT + 255) / 256, 256, 0, stream>>>(stats, FTOT);
    deg_kernel<<<eb, 256, 0, stream>>>(dstv, deg, E);
    scan_block<<<nb256, 256, 0, stream>>>(deg, part, bsum, N);
    scan_bsum<<<1, 256, 0, stream>>>(bsum, nb256);
    scan_fix<<<nb256, 256, 0, stream>>>(part, bsum, offs, cursor, N);
    fill_kernel<<<eb, 256, 0, stream>>>(srcv, dstv, cursor, eidx, E);
    cnt_kernel<<<(nb64 + 255) / 256, 256, 0, stream>>>(batch, cnt, N);

    // --- x -> bf16; weights -> fragment-ordered bf16 ---
    cvt_x<<<(N * 128 / 4 + 255) / 256, 256, 0, stream>>>(x, Xb, N * 128 / 4);
    u16* Wp1 = Wp + 32768;                      // 7 K=256 matrices after the K=128 one
    transw_frag<128><<<(128 * 32 + 255) / 256, 256, 0, stream>>>(w1a, Wp);
    transw_frag<256><<<(256 * 32 + 255) / 256, 256, 0, stream>>>(w1b, Wp1);
    for (int i = 0; i < 3; ++i) {
        transw_frag<256><<<(256 * 32 + 255) / 256, 256, 0, stream>>>(
            W_in + (size_t)i * 65536, Wp1 + (size_t)(1 + i) * 65536);
        transw_frag<256><<<(256 * 32 + 255) / 256, 256, 0, stream>>>(
            W_out + (size_t)i * 65536, Wp1 + (size_t)(4 + i) * 65536);
    }

    for (int L = 0; L < 4; ++L) {
        if (L == 0) {
            gin_fused<128><<<nbM, 256, 0, stream>>>(Xb, offs, eidx,
                Wp, b1a, Wp1, b1b, B0, stats, N);
        } else {
            gin_fused<256><<<nbM, 256, 0, stream>>>(B2, offs, eidx,
                Wp1 + (size_t)(1 + L - 1) * 65536, b_in + (L - 1) * 256,
                Wp1 + (size_t)(4 + L - 1) * 65536, b_out + (L - 1) * 256, B0, stats, N);
        }
        bn_pool<<<nb64, 256, 0, stream>>>(B0, stats, gamma + L * 256, beta + L * 256,
                                          batch, B2, pmax, psum, N);
        acc_update<<<(GNUM * 512) / 256, 256, 0, stream>>>(pmax, psum, cnt, acc, stats);
    }
    readout_kernel<<<GNUM, 256, 0, stream>>>(acc, l1w, l1b, l2w, l2b, l3w, l3b,
                                             (float*)d_out);
}

// Round 14
// 815.412 us; speedup vs baseline: 1.0891x; 1.0891x over previous
//
#include <hip/hip_runtime.h>
#include <hip/hip_bf16.h>

#define GNUM 64
#define BN_EPS 1e-5f

typedef unsigned short u16;
typedef unsigned int u32;
typedef __attribute__((ext_vector_type(8))) short short8;
typedef __attribute__((ext_vector_type(4))) float f32x4;

__device__ inline float bflo(u32 u) { union { u32 i; float f; } v; v.i = u << 16; return v.f; }
__device__ inline float bfhi(u32 u) { union { u32 i; float f; } v; v.i = u & 0xFFFF0000u; return v.f; }
__device__ inline u16 f2bf(float f) {
    union { float f; u32 i; } v; v.f = f;
    u32 x = v.i;
    return (u16)((x + 0x7FFFu + ((x >> 16) & 1u)) >> 16);  // RNE
}
__device__ inline u32 pack2(float a, float b) { return (u32)f2bf(a) | ((u32)f2bf(b) << 16); }
__device__ inline void acc8(float* a, uint4 v) {
    a[0] += bflo(v.x); a[1] += bfhi(v.x); a[2] += bflo(v.y); a[3] += bfhi(v.y);
    a[4] += bflo(v.z); a[5] += bfhi(v.z); a[6] += bflo(v.w); a[7] += bfhi(v.w);
}

// ---------------- zero-init ----------------
__global__ void zero_f(float* __restrict__ p, int n) {
    int i = blockIdx.x * 256 + threadIdx.x;
    if (i < n) p[i] = 0.f;
}
__global__ void zero_i(int* __restrict__ p, int n) {
    int i = blockIdx.x * 256 + threadIdx.x;
    if (i < n) p[i] = 0;
}

// ---------------- CSR build ----------------
__global__ void deg_kernel(const int* __restrict__ dst, int* __restrict__ deg, int E) {
    int e = blockIdx.x * 256 + threadIdx.x;
    if (e < E) atomicAdd(&deg[dst[e]], 1);
}

__global__ void scan_block(const int* __restrict__ deg, int* __restrict__ part,
                           int* __restrict__ bsum, int n) {
    __shared__ int tmp[256];
    int i = blockIdx.x * 256 + threadIdx.x;
    int v = (i < n) ? deg[i] : 0;
    tmp[threadIdx.x] = v;
    __syncthreads();
    for (int off = 1; off < 256; off <<= 1) {
        int x = 0;
        if (threadIdx.x >= off) x = tmp[threadIdx.x - off];
        __syncthreads();
        tmp[threadIdx.x] += x;
        __syncthreads();
    }
    if (i < n) part[i] = tmp[threadIdx.x];
    if (threadIdx.x == 255) bsum[blockIdx.x] = tmp[255];
}

__global__ void scan_bsum(int* __restrict__ bsum, int nb) {
    __shared__ int tmp[256];
    int v = (threadIdx.x < nb) ? bsum[threadIdx.x] : 0;
    tmp[threadIdx.x] = v;
    __syncthreads();
    for (int off = 1; off < 256; off <<= 1) {
        int x = 0;
        if (threadIdx.x >= off) x = tmp[threadIdx.x - off];
        __syncthreads();
        tmp[threadIdx.x] += x;
        __syncthreads();
    }
    if (threadIdx.x < nb) bsum[threadIdx.x] = tmp[threadIdx.x];
}

__global__ void scan_fix(const int* __restrict__ part, const int* __restrict__ bsum,
                         int* __restrict__ offs, int* __restrict__ cursor, int n) {
    int i = blockIdx.x * 256 + threadIdx.x;
    if (i >= n) return;
    int add = (blockIdx.x > 0) ? bsum[blockIdx.x - 1] : 0;
    int incl = part[i] + add;
    offs[i + 1] = incl;
    cursor[i + 1] = incl;
    if (i == 0) { offs[0] = 0; cursor[0] = 0; }
}

__global__ void fill_kernel(const int* __restrict__ src, const int* __restrict__ dst,
                            int* __restrict__ cursor, int* __restrict__ eidx, int E) {
    int e = blockIdx.x * 256 + threadIdx.x;
    if (e >= E) return;
    int d = dst[e];
    int p = atomicAdd(&cursor[d], 1);
    eidx[p] = src[e];
}

__global__ void cnt_kernel(const int* __restrict__ batch, float* __restrict__ cnt, int Nn) {
    int tid = blockIdx.x * blockDim.x + threadIdx.x;
    int s = tid * 64;
    if (s >= Nn) return;
    int e = min(s + 64, Nn);
    int cur = batch[s]; int run = 0;
    for (int r = s; r < e; ++r) {
        int b = batch[r];
        if (b != cur) { atomicAdd(&cnt[cur], (float)run); cur = b; run = 0; }
        run++;
    }
    atomicAdd(&cnt[cur], (float)run);
}

// ---------------- x fp32 -> bf16 ----------------
__global__ void cvt_x(const float* __restrict__ x, u16* __restrict__ xb, int total4) {
    int i = blockIdx.x * 256 + threadIdx.x;
    if (i >= total4) return;
    float4 v = *(const float4*)&x[i * 4];
    uint2 o;
    o.x = pack2(v.x, v.y);
    o.y = pack2(v.z, v.w);
    *(uint2*)&xb[i * 4] = o;
}

// ---------------- weight -> MFMA-fragment-ordered bf16 ----------------
// Wp short8 index o = ((t*(K/32) + kc)*8 + jf)*64 + l; element e:
//   k = kc*32 + (l>>4)*8 + e,  col = t*128 + jf*16 + (l&15)
template<int K>
__global__ void transw_frag(const float* __restrict__ W, u16* __restrict__ Wp) {
    int o = blockIdx.x * 256 + threadIdx.x;
    if (o >= K * 32) return;
    int l = o & 63;
    int q1 = o >> 6;
    int jf = q1 & 7;
    int q2 = q1 >> 3;
    const int KC = K / 32;
    int kc = q2 & (KC - 1);
    int t = q2 / KC;
    int kbase = kc * 32 + ((l >> 4) << 3);
    int col = t * 128 + jf * 16 + (l & 15);
#pragma unroll
    for (int e = 0; e < 8; ++e)
        Wp[(size_t)o * 8 + e] = f2bf(W[(size_t)(kbase + e) * 256 + col]);
}

// ---------------- aggregation v3: wave-per-node, LDS-free, 4-deep MLP ----------------
template<int F>
__global__ __launch_bounds__(256)
void agg3(const u16* __restrict__ h, const int* __restrict__ offs,
          const int* __restrict__ eidx, u16* __restrict__ z, int Nn) {
    const int CH = F / 8;               // 16B chunks per row (16 or 32)
    const int G = 64 / CH;              // edge groups per wave (4 or 2)
    int lane = threadIdx.x & 63;
    int n = blockIdx.x * 4 + (threadIdx.x >> 6);
    if (n >= Nn) return;
    int cc = lane & (CH - 1);
    int g = lane / CH;
    const u16* hp = h + cc * 8;

    float a[8] = {0.f, 0.f, 0.f, 0.f, 0.f, 0.f, 0.f, 0.f};
    if (g == 0) acc8(a, *(const uint4*)&hp[(size_t)n * F]);   // self term

    int j1 = offs[n + 1];
    int j = offs[n] + g;
    for (; j + 3 * G < j1; j += 4 * G) {
        int s0 = eidx[j], s1 = eidx[j + G], s2 = eidx[j + 2 * G], s3 = eidx[j + 3 * G];
        uint4 v0 = *(const uint4*)&hp[(size_t)s0 * F];
        uint4 v1 = *(const uint4*)&hp[(size_t)s1 * F];
        uint4 v2 = *(const uint4*)&hp[(size_t)s2 * F];
        uint4 v3 = *(const uint4*)&hp[(size_t)s3 * F];
        acc8(a, v0); acc8(a, v1); acc8(a, v2); acc8(a, v3);
    }
    for (; j < j1; j += G) {
        uint4 v = *(const uint4*)&hp[(size_t)eidx[j] * F];
        acc8(a, v);
    }
#pragma unroll
    for (int off = 32; off >= CH; off >>= 1)
#pragma unroll
        for (int e = 0; e < 8; ++e) a[e] += __shfl_down(a[e], off, 64);
    if (g == 0) {
        uint4 o;
        o.x = pack2(a[0], a[1]); o.y = pack2(a[2], a[3]);
        o.z = pack2(a[4], a[5]); o.w = pack2(a[6], a[7]);
        *(uint4*)&z[(size_t)n * F + cc * 8] = o;
    }
}

// ---------------- fused GIN-MLP v2: M=32 tile ------------------------------------
// out = (relu(z@W1+b1))@W2 + b2; stats += col sums. Block = 32 rows x 256 cols.
// 4 waves, wave w owns cols [w*64, w*64+64); each wave covers all 32 rows (2 m-frags).
// LDS ~42 KB (K=256) -> 3 blocks/CU; grid 2x round-12 for latency hiding.
template<int K1>
__global__ __launch_bounds__(256, 3)
void gin_mlp(const u16* __restrict__ Z, const u16* __restrict__ W1p,
             const float* __restrict__ b1, const u16* __restrict__ W2p,
             const float* __restrict__ b2, u16* __restrict__ Cout,
             float* __restrict__ stats, int M) {
    constexpr int KC1 = K1 / 32;
    __shared__ u16 As[32 * K1];         // z tile, frag-major (2 m-frags)
    __shared__ u16 Hs[32 * 256];        // h1 tile, A-frag layout for GEMM2
    __shared__ u16 tbuf[4608];          // 4 waves x 16 rows x 72 u16
    __shared__ float cs[256];
    int t = threadIdx.x;
    int lane = t & 63, wave = t >> 6;
    int m0 = blockIdx.x * 32;
    int lm = lane & 15, q = lane >> 4;

    // --- phase 0: stage z. Thread t: row t>>3 (0..31), seg t&7 (K1/8 u16 contig) ---
    {
        int row = t >> 3, s = t & 7;
        int gr = m0 + row; if (gr >= M) gr = M - 1;
        const u16* gp = Z + (size_t)gr * K1 + s * (K1 / 8);
        int mf = row >> 4, r15 = row & 15;
#pragma unroll
        for (int j = 0; j < K1 / 64; ++j) {   // chunks of 8 u16 per thread
            uint4 v = *(const uint4*)(gp + j * 8);
            int c = s * (K1 / 64) + j;        // chunk index within row
            int kc = c >> 2, qq = c & 3;
            *(uint4*)&As[((mf * KC1 + kc) * 64 + r15 + (qq << 4)) * 8] = v;
        }
    }
    __syncthreads();

    f32x4 acc[2][4];
#pragma unroll
    for (int i = 0; i < 2; ++i)
#pragma unroll
        for (int j = 0; j < 4; ++j) acc[i][j] = (f32x4)0.0f;

    // --- phase 1: GEMM1. wave w: cols w*64.. ---
    {
        const u16* bbase = W1p + ((((size_t)(wave >> 1) * KC1) * 8 + ((wave & 1) << 2)) * 64 + lane) * 8;
        short8 a0[2], a1[2], b0[4], b1r[4];
#pragma unroll
        for (int i = 0; i < 2; ++i) a0[i] = *(const short8*)&As[(i * KC1) * 512 + lane * 8];
#pragma unroll
        for (int j = 0; j < 4; ++j) b0[j] = *(const short8*)(bbase + j * 512);
#pragma unroll
        for (int kc = 0; kc < KC1; ++kc) {
            short8* ac = (kc & 1) ? a1 : a0;
            short8* bc = (kc & 1) ? b1r : b0;
            short8* an = (kc & 1) ? a0 : a1;
            short8* bn = (kc & 1) ? b0 : b1r;
            if (kc + 1 < KC1) {
#pragma unroll
                for (int i = 0; i < 2; ++i)
                    an[i] = *(const short8*)&As[(i * KC1 + kc + 1) * 512 + lane * 8];
#pragma unroll
                for (int j = 0; j < 4; ++j)
                    bn[j] = *(const short8*)(bbase + (size_t)(kc + 1) * 4096 + j * 512);
            }
#pragma unroll
            for (int i = 0; i < 2; ++i)
#pragma unroll
                for (int j = 0; j < 4; ++j)
                    acc[i][j] = __builtin_amdgcn_mfma_f32_16x16x32_bf16(ac[i], bc[j], acc[i][j], 0, 0, 0);
        }
    }

    // --- phase 2: h1 = relu(acc + b1) -> Hs in A-frag layout ---
    // C/D: row = i*16 + q*4 + r, col = w*64 + j*16 + lm.
    // A-frag: Hs[((mf*8 + kc)*64 + r15 + qq*16)*8 + e],
    //   mf=i, r15=q*4+r, kc=w*2+(j>>1), qq=(j&1)*2+(lm>>3), e=lm&7.
    {
#pragma unroll
        for (int j = 0; j < 4; ++j) {
            float bv = b1[wave * 64 + j * 16 + lm];
            int kc = wave * 2 + (j >> 1);
            int qq = ((j & 1) << 1) + (lm >> 3);
            int e = lm & 7;
#pragma unroll
            for (int i = 0; i < 2; ++i) {
#pragma unroll
                for (int r = 0; r < 4; ++r) {
                    float v = fmaxf(acc[i][j][r] + bv, 0.f);
                    Hs[(((i * 8 + kc) * 64) + (q * 4 + r) + qq * 16) * 8 + e] = f2bf(v);
                }
            }
        }
    }
    __syncthreads();

    // --- phase 3: GEMM2 (K = 256, A from Hs) ---
#pragma unroll
    for (int i = 0; i < 2; ++i)
#pragma unroll
        for (int j = 0; j < 4; ++j) acc[i][j] = (f32x4)0.0f;
    {
        const u16* bbase = W2p + ((((size_t)(wave >> 1) * 8) * 8 + ((wave & 1) << 2)) * 64 + lane) * 8;
        short8 a0[2], a1[2], b0[4], b1r[4];
#pragma unroll
        for (int i = 0; i < 2; ++i) a0[i] = *(const short8*)&Hs[(i * 8) * 512 + lane * 8];
#pragma unroll
        for (int j = 0; j < 4; ++j) b0[j] = *(const short8*)(bbase + j * 512);
#pragma unroll
        for (int kc = 0; kc < 8; ++kc) {
            short8* ac = (kc & 1) ? a1 : a0;
            short8* bc = (kc & 1) ? b1r : b0;
            short8* an = (kc & 1) ? a0 : a1;
            short8* bn = (kc & 1) ? b0 : b1r;
            if (kc + 1 < 8) {
#pragma unroll
                for (int i = 0; i < 2; ++i)
                    an[i] = *(const short8*)&Hs[(i * 8 + kc + 1) * 512 + lane * 8];
#pragma unroll
                for (int j = 0; j < 4; ++j)
                    bn[j] = *(const short8*)(bbase + (size_t)(kc + 1) * 4096 + j * 512);
            }
#pragma unroll
            for (int i = 0; i < 2; ++i)
#pragma unroll
                for (int j = 0; j < 4; ++j)
                    acc[i][j] = __builtin_amdgcn_mfma_f32_16x16x32_bf16(ac[i], bc[j], acc[i][j], 0, 0, 0);
        }
    }

    // --- epilogue: v5.1-proven transpose; stats always ---
    float bv2[4], s_sum[4], s_sq[4];
#pragma unroll
    for (int j = 0; j < 4; ++j) {
        bv2[j] = b2[wave * 64 + j * 16 + lm];
        s_sum[j] = 0.f; s_sq[j] = 0.f;
    }
#pragma unroll
    for (int i = 0; i < 2; ++i) {
#pragma unroll
        for (int j = 0; j < 4; ++j) {
#pragma unroll
            for (int r = 0; r < 4; ++r) {
                int row = m0 + i * 16 + q * 4 + r;
                float v = acc[i][j][r] + bv2[j];
                if (row < M) { s_sum[j] += v; s_sq[j] = fmaf(v, v, s_sq[j]); }
                tbuf[wave * 1152 + (q * 4 + r) * 72 + j * 16 + lm] = f2bf(v);
            }
        }
        __syncthreads();
        int rl = lane >> 2, seg = lane & 3;
        uint4 w0 = *(const uint4*)&tbuf[wave * 1152 + rl * 72 + seg * 16];
        uint4 w1 = *(const uint4*)&tbuf[wave * 1152 + rl * 72 + seg * 16 + 8];
        int rowg = m0 + i * 16 + rl;
        if (rowg < M) {
            u16* cp = Cout + (size_t)rowg * 256 + wave * 64 + seg * 16;
            *(uint4*)cp = w0;
            *(uint4*)(cp + 8) = w1;
        }
        __syncthreads();
    }

    cs[t] = 0.f;
    __syncthreads();
#pragma unroll
    for (int j = 0; j < 4; ++j)
        atomicAdd(&cs[wave * 64 + j * 16 + lm], s_sum[j]);
    __syncthreads();
    atomicAdd(&stats[t], cs[t]);
    __syncthreads();
    cs[t] = 0.f;
    __syncthreads();
#pragma unroll
    for (int j = 0; j < 4; ++j)
        atomicAdd(&cs[wave * 64 + j * 16 + lm], s_sq[j]);
    __syncthreads();
    atomicAdd(&stats[256 + t], cs[t]);
}

// ---------------- BN apply + ReLU + segmented max/sum pool ----------------
__global__ __launch_bounds__(256)
void bn_pool(const u16* __restrict__ Z, const float* __restrict__ stats,
             const float* __restrict__ gamma, const float* __restrict__ beta,
             const int* __restrict__ batch, u16* __restrict__ H,
             float* __restrict__ pool_max, float* __restrict__ pool_sum, int Nn) {
    int col = threadIdx.x;
    int r0 = blockIdx.x * 64;
    if (r0 >= Nn) return;
    float mu = stats[col] / (float)Nn;
    float var = stats[256 + col] / (float)Nn - mu * mu;
    float scale = gamma[col] * rsqrtf(var + BN_EPS);
    float shift = beta[col] - mu * scale;
    int rend = min(r0 + 64, Nn);
    int cur = batch[r0];
    float rmax = 0.f, rsum = 0.f;
    for (int r = r0; r < rend; ++r) {
        int bb = batch[r];
        if (bb != cur) {
            atomicMax((int*)&pool_max[cur * 256 + col], __float_as_int(rmax));
            atomicAdd(&pool_sum[cur * 256 + col], rsum);
            cur = bb; rmax = 0.f; rsum = 0.f;
        }
        float v = fmaf(bflo(Z[(size_t)r * 256 + col]), scale, shift);
        v = fmaxf(v, 0.f);  // >=0 so int atomicMax on float bits is valid
        H[(size_t)r * 256 + col] = f2bf(v);
        rmax = fmaxf(rmax, v); rsum += v;
    }
    atomicMax((int*)&pool_max[cur * 256 + col], __float_as_int(rmax));
    atomicAdd(&pool_sum[cur * 256 + col], rsum);
}

// ---------------- acc += concat(max, mean); reset pmax/psum/stats for next layer ----------------
__global__ void acc_update(float* __restrict__ pmax, float* __restrict__ psum,
                           const float* __restrict__ cnt, float* __restrict__ acc,
                           float* __restrict__ stats) {
    int i = blockIdx.x * 256 + threadIdx.x;  // GNUM*512 total
    int g = i >> 9, c = i & 511;
    float v;
    if (c < 256) {
        v = pmax[g * 256 + c];
        pmax[g * 256 + c] = 0.f;
    } else {
        int cc = c - 256;
        v = psum[g * 256 + cc] / fmaxf(cnt[g], 1.f);
        psum[g * 256 + cc] = 0.f;
    }
    acc[i] += v;
    if (i < 512) stats[i] = 0.f;
}

// ---------------- fused readout MLP (fp32): [64,512]->256->128->250 ----------------
__global__ __launch_bounds__(256)
void readout_kernel(const float* __restrict__ acc,
                    const float* __restrict__ w1, const float* __restrict__ b1,
                    const float* __restrict__ w2, const float* __restrict__ b2,
                    const float* __restrict__ w3, const float* __restrict__ b3,
                    float* __restrict__ out) {
    __shared__ float a[512], z1[256], z2[128];
    int g = blockIdx.x, t = threadIdx.x;
    a[t] = acc[g * 512 + t];
    a[t + 256] = acc[g * 512 + 256 + t];
    __syncthreads();
    float s = b1[t];
    for (int k = 0; k < 512; ++k) s = fmaf(a[k], w1[k * 256 + t], s);
    z1[t] = fmaxf(s, 0.f);
    __syncthreads();
    if (t < 128) {
        float s2 = b2[t];
        for (int k = 0; k < 256; ++k) s2 = fmaf(z1[k], w2[k * 128 + t], s2);
        z2[t] = fmaxf(s2, 0.f);
    }
    __syncthreads();
    if (t < 250) {
        float s3 = b3[t];
        for (int k = 0; k < 128; ++k) s3 = fmaf(z2[k], w3[k * 250 + t], s3);
        out[g * 250 + t] = s3;
    }
}

extern "C" void kernel_launch(void* const* d_in, const int* in_sizes, int n_in,
                              void* d_out, int out_size, void* d_ws, size_t ws_size,
                              hipStream_t stream) {
    const float* x     = (const float*)d_in[0];
    const int* ei      = (const int*)d_in[1];
    const int* batch   = (const int*)d_in[2];
    const float* w1a   = (const float*)d_in[3];
    const float* b1a   = (const float*)d_in[4];
    const float* w1b   = (const float*)d_in[5];
    const float* b1b   = (const float*)d_in[6];
    const float* W_in  = (const float*)d_in[7];
    const float* b_in  = (const float*)d_in[8];
    const float* W_out = (const float*)d_in[9];
    const float* b_out = (const float*)d_in[10];
    const float* gamma = (const float*)d_in[11];
    const float* beta  = (const float*)d_in[12];
    const float* l1w   = (const float*)d_in[13];
    const float* l1b   = (const float*)d_in[14];
    const float* l2w   = (const float*)d_in[15];
    const float* l2b   = (const float*)d_in[16];
    const float* l3w   = (const float*)d_in[17];
    const float* l3b   = (const float*)d_in[18];

    const int N = in_sizes[2];
    const int E = in_sizes[1] / 2;
    const int* srcv = ei;
    const int* dstv = ei + E;

    // ---- workspace layout (~82 MB) ----
    u16* B0 = (u16*)d_ws;                       // N*256 bf16 (z / z2 in-place L>=1)
    u16* B1 = B0 + (size_t)N * 256;             // N*256 bf16 (Xb first half; L0 out)
    u16* B2 = B1 + (size_t)N * 256;             // N*256 bf16 (post-BN H)
    u16* Xb = B1;                               // N*128 bf16
    u16* Wp = B2 + (size_t)N * 256;             // 32768 + 7*65536 u16 frag-ordered weights
    float* stats = (float*)(Wp + 32768 + 7 * 65536);  // 512
    float* pmax  = stats + 512;                 // 16384
    float* psum  = pmax + GNUM * 256;           // 16384
    float* acc   = psum + GNUM * 256;           // 32768
    float* cnt   = acc + GNUM * 512;            // 64
    int* deg    = (int*)(cnt + GNUM);           // N
    int* part   = deg + N;                      // N
    int* bsum   = part + N;                     // 256
    int* offs   = bsum + 256;                   // N+1
    int* cursor = offs + N + 1;                 // N+1
    int* eidx   = cursor + N + 1;               // E

    int nb256 = (N + 255) / 256;
    int nbM   = (N + 31) / 32;
    int nb64  = (N + 63) / 64;
    int nbW   = (N + 3) / 4;
    int eb    = (E + 255) / 256;
    const int FTOT = 512 + GNUM * 256 * 2 + GNUM * 512 + GNUM;  // 66112

    // --- init + CSR build + per-graph counts ---
    zero_i<<<nb256, 256, 0, stream>>>(deg, N);
    zero_f<<<(FTOT + 255) / 256, 256, 0, stream>>>(stats, FTOT);
    deg_kernel<<<eb, 256, 0, stream>>>(dstv, deg, E);
    scan_block<<<nb256, 256, 0, stream>>>(deg, part, bsum, N);
    scan_bsum<<<1, 256, 0, stream>>>(bsum, nb256);
    scan_fix<<<nb256, 256, 0, stream>>>(part, bsum, offs, cursor, N);
    fill_kernel<<<eb, 256, 0, stream>>>(srcv, dstv, cursor, eidx, E);
    cnt_kernel<<<(nb64 + 255) / 256, 256, 0, stream>>>(batch, cnt, N);

    // --- x -> bf16; weights -> fragment-ordered bf16 ---
    cvt_x<<<(N * 128 / 4 + 255) / 256, 256, 0, stream>>>(x, Xb, N * 128 / 4);
    u16* Wp1 = Wp + 32768;                      // 7 K=256 matrices after the K=128 one
    transw_frag<128><<<(128 * 32 + 255) / 256, 256, 0, stream>>>(w1a, Wp);
    transw_frag<256><<<(256 * 32 + 255) / 256, 256, 0, stream>>>(w1b, Wp1);
    for (int i = 0; i < 3; ++i) {
        transw_frag<256><<<(256 * 32 + 255) / 256, 256, 0, stream>>>(
            W_in + (size_t)i * 65536, Wp1 + (size_t)(1 + i) * 65536);
        transw_frag<256><<<(256 * 32 + 255) / 256, 256, 0, stream>>>(
            W_out + (size_t)i * 65536, Wp1 + (size_t)(4 + i) * 65536);
    }

    for (int L = 0; L < 4; ++L) {
        if (L == 0) {
            agg3<128><<<nbW, 256, 0, stream>>>(Xb, offs, eidx, B0, N);
            gin_mlp<128><<<nbM, 256, 0, stream>>>(B0, Wp, b1a, Wp1, b1b, B1, stats, N);
            bn_pool<<<nb64, 256, 0, stream>>>(B1, stats, gamma, beta,
                                              batch, B2, pmax, psum, N);
        } else {
            agg3<256><<<nbW, 256, 0, stream>>>(B2, offs, eidx, B0, N);
            gin_mlp<256><<<nbM, 256, 0, stream>>>(
                B0, Wp1 + (size_t)(1 + L - 1) * 65536, b_in + (L - 1) * 256,
                Wp1 + (size_t)(4 + L - 1) * 65536, b_out + (L - 1) * 256, B0, stats, N);
            bn_pool<<<nb64, 256, 0, stream>>>(B0, stats, gamma + L * 256, beta + L * 256,
                                              batch, B2, pmax, psum, N);
        }
        acc_update<<<(GNUM * 512) / 256, 256, 0, stream>>>(pmax, psum, cnt, acc, stats);
    }
    readout_kernel<<<GNUM, 256, 0, stream>>>(acc, l1w, l1b, l2w, l2b, l3w, l3b,
                                             (float*)d_out);
}

// Round 15
// 708.543 us; speedup vs baseline: 1.2534x; 1.1508x over previous
//
#include <hip/hip_runtime.h>
#include <hip/hip_bf16.h>

#define GNUM 64
#define BN_EPS 1e-5f

typedef unsigned short u16;
typedef unsigned int u32;
typedef __attribute__((ext_vector_type(8))) short short8;
typedef __attribute__((ext_vector_type(4))) float f32x4;

__device__ inline float bflo(u32 u) { union { u32 i; float f; } v; v.i = u << 16; return v.f; }
__device__ inline float bfhi(u32 u) { union { u32 i; float f; } v; v.i = u & 0xFFFF0000u; return v.f; }
__device__ inline u16 f2bf(float f) {
    union { float f; u32 i; } v; v.f = f;
    u32 x = v.i;
    return (u16)((x + 0x7FFFu + ((x >> 16) & 1u)) >> 16);  // RNE
}
__device__ inline u32 pack2(float a, float b) { return (u32)f2bf(a) | ((u32)f2bf(b) << 16); }
__device__ inline void acc8(float* a, uint4 v) {
    a[0] += bflo(v.x); a[1] += bfhi(v.x); a[2] += bflo(v.y); a[3] += bfhi(v.y);
    a[4] += bflo(v.z); a[5] += bfhi(v.z); a[6] += bflo(v.w); a[7] += bfhi(v.w);
}

// ---------------- zero-init ----------------
__global__ void zero_f(float* __restrict__ p, int n) {
    int i = blockIdx.x * 256 + threadIdx.x;
    if (i < n) p[i] = 0.f;
}
__global__ void zero_i(int* __restrict__ p, int n) {
    int i = blockIdx.x * 256 + threadIdx.x;
    if (i < n) p[i] = 0;
}

// ---------------- CSR build ----------------
__global__ void deg_kernel(const int* __restrict__ dst, int* __restrict__ deg, int E) {
    int e = blockIdx.x * 256 + threadIdx.x;
    if (e < E) atomicAdd(&deg[dst[e]], 1);
}

__global__ void scan_block(const int* __restrict__ deg, int* __restrict__ part,
                           int* __restrict__ bsum, int n) {
    __shared__ int tmp[256];
    int i = blockIdx.x * 256 + threadIdx.x;
    int v = (i < n) ? deg[i] : 0;
    tmp[threadIdx.x] = v;
    __syncthreads();
    for (int off = 1; off < 256; off <<= 1) {
        int x = 0;
        if (threadIdx.x >= off) x = tmp[threadIdx.x - off];
        __syncthreads();
        tmp[threadIdx.x] += x;
        __syncthreads();
    }
    if (i < n) part[i] = tmp[threadIdx.x];
    if (threadIdx.x == 255) bsum[blockIdx.x] = tmp[255];
}

__global__ void scan_bsum(int* __restrict__ bsum, int nb) {
    __shared__ int tmp[256];
    int v = (threadIdx.x < nb) ? bsum[threadIdx.x] : 0;
    tmp[threadIdx.x] = v;
    __syncthreads();
    for (int off = 1; off < 256; off <<= 1) {
        int x = 0;
        if (threadIdx.x >= off) x = tmp[threadIdx.x - off];
        __syncthreads();
        tmp[threadIdx.x] += x;
        __syncthreads();
    }
    if (threadIdx.x < nb) bsum[threadIdx.x] = tmp[threadIdx.x];
}

__global__ void scan_fix(const int* __restrict__ part, const int* __restrict__ bsum,
                         int* __restrict__ offs, int* __restrict__ cursor, int n) {
    int i = blockIdx.x * 256 + threadIdx.x;
    if (i >= n) return;
    int add = (blockIdx.x > 0) ? bsum[blockIdx.x - 1] : 0;
    int incl = part[i] + add;
    offs[i + 1] = incl;
    cursor[i + 1] = incl;
    if (i == 0) { offs[0] = 0; cursor[0] = 0; }
}

__global__ void fill_kernel(const int* __restrict__ src, const int* __restrict__ dst,
                            int* __restrict__ cursor, int* __restrict__ eidx, int E) {
    int e = blockIdx.x * 256 + threadIdx.x;
    if (e >= E) return;
    int d = dst[e];
    int p = atomicAdd(&cursor[d], 1);
    eidx[p] = src[e];
}

__global__ void cnt_kernel(const int* __restrict__ batch, float* __restrict__ cnt, int Nn) {
    int tid = blockIdx.x * blockDim.x + threadIdx.x;
    int s = tid * 64;
    if (s >= Nn) return;
    int e = min(s + 64, Nn);
    int cur = batch[s]; int run = 0;
    for (int r = s; r < e; ++r) {
        int b = batch[r];
        if (b != cur) { atomicAdd(&cnt[cur], (float)run); cur = b; run = 0; }
        run++;
    }
    atomicAdd(&cnt[cur], (float)run);
}

// ---------------- x fp32 -> bf16 ----------------
__global__ void cvt_x(const float* __restrict__ x, u16* __restrict__ xb, int total4) {
    int i = blockIdx.x * 256 + threadIdx.x;
    if (i >= total4) return;
    float4 v = *(const float4*)&x[i * 4];
    uint2 o;
    o.x = pack2(v.x, v.y);
    o.y = pack2(v.z, v.w);
    *(uint2*)&xb[i * 4] = o;
}

// ---------------- weight -> MFMA-fragment-ordered bf16 ----------------
// Wp short8 index o = ((t*(K/32) + kc)*8 + jf)*64 + l; element e:
//   k = kc*32 + (l>>4)*8 + e,  col = t*128 + jf*16 + (l&15)
template<int K>
__global__ void transw_frag(const float* __restrict__ W, u16* __restrict__ Wp) {
    int o = blockIdx.x * 256 + threadIdx.x;
    if (o >= K * 32) return;
    int l = o & 63;
    int q1 = o >> 6;
    int jf = q1 & 7;
    int q2 = q1 >> 3;
    const int KC = K / 32;
    int kc = q2 & (KC - 1);
    int t = q2 / KC;
    int kbase = kc * 32 + ((l >> 4) << 3);
    int col = t * 128 + jf * 16 + (l & 15);
#pragma unroll
    for (int e = 0; e < 8; ++e)
        Wp[(size_t)o * 8 + e] = f2bf(W[(size_t)(kbase + e) * 256 + col]);
}

// ---------------- aggregation v3: wave-per-node, LDS-free, 4-deep MLP ----------------
template<int F>
__global__ __launch_bounds__(256)
void agg3(const u16* __restrict__ h, const int* __restrict__ offs,
          const int* __restrict__ eidx, u16* __restrict__ z, int Nn) {
    const int CH = F / 8;               // 16B chunks per row (16 or 32)
    const int G = 64 / CH;              // edge groups per wave (4 or 2)
    int lane = threadIdx.x & 63;
    int n = blockIdx.x * 4 + (threadIdx.x >> 6);
    if (n >= Nn) return;
    int cc = lane & (CH - 1);
    int g = lane / CH;
    const u16* hp = h + cc * 8;

    float a[8] = {0.f, 0.f, 0.f, 0.f, 0.f, 0.f, 0.f, 0.f};
    if (g == 0) acc8(a, *(const uint4*)&hp[(size_t)n * F]);   // self term

    int j1 = offs[n + 1];
    int j = offs[n] + g;
    for (; j + 3 * G < j1; j += 4 * G) {
        int s0 = eidx[j], s1 = eidx[j + G], s2 = eidx[j + 2 * G], s3 = eidx[j + 3 * G];
        uint4 v0 = *(const uint4*)&hp[(size_t)s0 * F];
        uint4 v1 = *(const uint4*)&hp[(size_t)s1 * F];
        uint4 v2 = *(const uint4*)&hp[(size_t)s2 * F];
        uint4 v3 = *(const uint4*)&hp[(size_t)s3 * F];
        acc8(a, v0); acc8(a, v1); acc8(a, v2); acc8(a, v3);
    }
    for (; j < j1; j += G) {
        uint4 v = *(const uint4*)&hp[(size_t)eidx[j] * F];
        acc8(a, v);
    }
#pragma unroll
    for (int off = 32; off >= CH; off >>= 1)
#pragma unroll
        for (int e = 0; e < 8; ++e) a[e] += __shfl_down(a[e], off, 64);
    if (g == 0) {
        uint4 o;
        o.x = pack2(a[0], a[1]); o.y = pack2(a[2], a[3]);
        o.z = pack2(a[4], a[5]); o.w = pack2(a[6], a[7]);
        *(uint4*)&z[(size_t)n * F + cc * 8] = o;
    }
}

// ---------------- fused GIN-MLP (round-12 best): M=64 tile --------------------------
// out = (relu(z@W1+b1))@W2 + b2; stats += col sums. Block = 64 rows x full 256 cols.
template<int K1>
__global__ __launch_bounds__(256, 2)
void gin_mlp(const u16* __restrict__ Z, const u16* __restrict__ W1p,
             const float* __restrict__ b1, const u16* __restrict__ W2p,
             const float* __restrict__ b2, u16* __restrict__ Cout,
             float* __restrict__ stats, int M) {
    constexpr int KC1 = K1 / 32;
    __shared__ u16 As[64 * K1];         // z tile, frag-major
    __shared__ u16 Hs[64 * 256];        // h1 tile, A-frag layout for GEMM2
    __shared__ u16 tbuf[4608];          // 4 waves x 16 rows x 72 u16
    __shared__ float cs[256];
    int t = threadIdx.x;
    int lane = t & 63, wave = t >> 6;
    int m0 = blockIdx.x * 64;
    int lm = lane & 15, q = lane >> 4;

    // --- phase 0: stage z (thread t: row t>>2, seg t&3, K1/4 u16 contiguous) ---
    {
        int row = t >> 2, s = t & 3;
        int gr = m0 + row; if (gr >= M) gr = M - 1;
        const u16* gp = Z + (size_t)gr * K1 + s * (K1 / 4);
        int mf = row >> 4, r15 = row & 15;
#pragma unroll
        for (int j = 0; j < K1 / 32; ++j) {
            uint4 v = *(const uint4*)(gp + j * 8);
            int c = s * (K1 / 32) + j;
            int kc = c >> 2, qq = c & 3;
            *(uint4*)&As[((mf * KC1 + kc) * 64 + r15 + (qq << 4)) * 8] = v;
        }
    }
    __syncthreads();

    f32x4 acc[4][4];
#pragma unroll
    for (int i = 0; i < 4; ++i)
#pragma unroll
        for (int j = 0; j < 4; ++j) acc[i][j] = (f32x4)0.0f;

    // --- phase 1: GEMM1. wave w: cols w*64.. ---
    {
        const u16* bbase = W1p + ((((size_t)(wave >> 1) * KC1) * 8 + ((wave & 1) << 2)) * 64 + lane) * 8;
        short8 a0[4], a1[4], b0[4], b1r[4];
#pragma unroll
        for (int i = 0; i < 4; ++i) a0[i] = *(const short8*)&As[(i * KC1) * 512 + lane * 8];
#pragma unroll
        for (int j = 0; j < 4; ++j) b0[j] = *(const short8*)(bbase + j * 512);
#pragma unroll
        for (int kc = 0; kc < KC1; ++kc) {
            short8* ac = (kc & 1) ? a1 : a0;
            short8* bc = (kc & 1) ? b1r : b0;
            short8* an = (kc & 1) ? a0 : a1;
            short8* bn = (kc & 1) ? b0 : b1r;
            if (kc + 1 < KC1) {
#pragma unroll
                for (int i = 0; i < 4; ++i)
                    an[i] = *(const short8*)&As[(i * KC1 + kc + 1) * 512 + lane * 8];
#pragma unroll
                for (int j = 0; j < 4; ++j)
                    bn[j] = *(const short8*)(bbase + (size_t)(kc + 1) * 4096 + j * 512);
            }
#pragma unroll
            for (int i = 0; i < 4; ++i)
#pragma unroll
                for (int j = 0; j < 4; ++j)
                    acc[i][j] = __builtin_amdgcn_mfma_f32_16x16x32_bf16(ac[i], bc[j], acc[i][j], 0, 0, 0);
        }
    }

    // --- phase 2: h1 = relu(acc + b1) -> Hs in A-frag layout ---
    // C/D: row = i*16 + q*4 + r, col = w*64 + j*16 + lm.
    // A-frag: Hs[((mf*8 + kc)*64 + r15 + qq*16)*8 + e],
    //   mf=i, r15=q*4+r, kc=w*2+(j>>1), qq=(j&1)*2+(lm>>3), e=lm&7.
    {
#pragma unroll
        for (int j = 0; j < 4; ++j) {
            float bv = b1[wave * 64 + j * 16 + lm];
            int kc = wave * 2 + (j >> 1);
            int qq = ((j & 1) << 1) + (lm >> 3);
            int e = lm & 7;
#pragma unroll
            for (int i = 0; i < 4; ++i) {
#pragma unroll
                for (int r = 0; r < 4; ++r) {
                    float v = fmaxf(acc[i][j][r] + bv, 0.f);
                    Hs[(((i * 8 + kc) * 64) + (q * 4 + r) + qq * 16) * 8 + e] = f2bf(v);
                }
            }
        }
    }
    __syncthreads();

    // --- phase 3: GEMM2 (K = 256, A from Hs) ---
#pragma unroll
    for (int i = 0; i < 4; ++i)
#pragma unroll
        for (int j = 0; j < 4; ++j) acc[i][j] = (f32x4)0.0f;
    {
        const u16* bbase = W2p + ((((size_t)(wave >> 1) * 8) * 8 + ((wave & 1) << 2)) * 64 + lane) * 8;
        short8 a0[4], a1[4], b0[4], b1r[4];
#pragma unroll
        for (int i = 0; i < 4; ++i) a0[i] = *(const short8*)&Hs[(i * 8) * 512 + lane * 8];
#pragma unroll
        for (int j = 0; j < 4; ++j) b0[j] = *(const short8*)(bbase + j * 512);
#pragma unroll
        for (int kc = 0; kc < 8; ++kc) {
            short8* ac = (kc & 1) ? a1 : a0;
            short8* bc = (kc & 1) ? b1r : b0;
            short8* an = (kc & 1) ? a0 : a1;
            short8* bn = (kc & 1) ? b0 : b1r;
            if (kc + 1 < 8) {
#pragma unroll
                for (int i = 0; i < 4; ++i)
                    an[i] = *(const short8*)&Hs[(i * 8 + kc + 1) * 512 + lane * 8];
#pragma unroll
                for (int j = 0; j < 4; ++j)
                    bn[j] = *(const short8*)(bbase + (size_t)(kc + 1) * 4096 + j * 512);
            }
#pragma unroll
            for (int i = 0; i < 4; ++i)
#pragma unroll
                for (int j = 0; j < 4; ++j)
                    acc[i][j] = __builtin_amdgcn_mfma_f32_16x16x32_bf16(ac[i], bc[j], acc[i][j], 0, 0, 0);
        }
    }

    // --- epilogue: v5.1-proven transpose; stats always ---
    float bv2[4], s_sum[4], s_sq[4];
#pragma unroll
    for (int j = 0; j < 4; ++j) {
        bv2[j] = b2[wave * 64 + j * 16 + lm];
        s_sum[j] = 0.f; s_sq[j] = 0.f;
    }
#pragma unroll
    for (int i = 0; i < 4; ++i) {
#pragma unroll
        for (int j = 0; j < 4; ++j) {
#pragma unroll
            for (int r = 0; r < 4; ++r) {
                int row = m0 + i * 16 + q * 4 + r;
                float v = acc[i][j][r] + bv2[j];
                if (row < M) { s_sum[j] += v; s_sq[j] = fmaf(v, v, s_sq[j]); }
                tbuf[wave * 1152 + (q * 4 + r) * 72 + j * 16 + lm] = f2bf(v);
            }
        }
        __syncthreads();
        int rl = lane >> 2, seg = lane & 3;
        uint4 w0 = *(const uint4*)&tbuf[wave * 1152 + rl * 72 + seg * 16];
        uint4 w1 = *(const uint4*)&tbuf[wave * 1152 + rl * 72 + seg * 16 + 8];
        int rowg = m0 + i * 16 + rl;
        if (rowg < M) {
            u16* cp = Cout + (size_t)rowg * 256 + wave * 64 + seg * 16;
            *(uint4*)cp = w0;
            *(uint4*)(cp + 8) = w1;
        }
        __syncthreads();
    }

    cs[t] = 0.f;
    __syncthreads();
#pragma unroll
    for (int j = 0; j < 4; ++j)
        atomicAdd(&cs[wave * 64 + j * 16 + lm], s_sum[j]);
    __syncthreads();
    atomicAdd(&stats[t], cs[t]);
    __syncthreads();
    cs[t] = 0.f;
    __syncthreads();
#pragma unroll
    for (int j = 0; j < 4; ++j)
        atomicAdd(&cs[wave * 64 + j * 16 + lm], s_sq[j]);
    __syncthreads();
    atomicAdd(&stats[256 + t], cs[t]);
}

// ---------------- BN apply + ReLU + segmented max/sum pool (16 rows/block) ---------
__global__ __launch_bounds__(256)
void bn_pool(const u16* __restrict__ Z, const float* __restrict__ stats,
             const float* __restrict__ gamma, const float* __restrict__ beta,
             const int* __restrict__ batch, u16* __restrict__ H,
             float* __restrict__ pool_max, float* __restrict__ pool_sum, int Nn) {
    int col = threadIdx.x;
    int r0 = blockIdx.x * 16;           // 16 rows/block: 4x parallelism vs 64
    if (r0 >= Nn) return;
    float mu = stats[col] / (float)Nn;
    float var = stats[256 + col] / (float)Nn - mu * mu;
    float scale = gamma[col] * rsqrtf(var + BN_EPS);
    float shift = beta[col] - mu * scale;
    int rend = min(r0 + 16, Nn);
    int cur = batch[r0];
    float rmax = 0.f, rsum = 0.f;
    for (int r = r0; r < rend; ++r) {
        int bb = batch[r];
        if (bb != cur) {
            atomicMax((int*)&pool_max[cur * 256 + col], __float_as_int(rmax));
            atomicAdd(&pool_sum[cur * 256 + col], rsum);
            cur = bb; rmax = 0.f; rsum = 0.f;
        }
        float v = fmaf(bflo(Z[(size_t)r * 256 + col]), scale, shift);
        v = fmaxf(v, 0.f);  // >=0 so int atomicMax on float bits is valid
        H[(size_t)r * 256 + col] = f2bf(v);
        rmax = fmaxf(rmax, v); rsum += v;
    }
    atomicMax((int*)&pool_max[cur * 256 + col], __float_as_int(rmax));
    atomicAdd(&pool_sum[cur * 256 + col], rsum);
}

// ---------------- acc += concat(max, mean); reset pmax/psum/stats for next layer ----------------
__global__ void acc_update(float* __restrict__ pmax, float* __restrict__ psum,
                           const float* __restrict__ cnt, float* __restrict__ acc,
                           float* __restrict__ stats) {
    int i = blockIdx.x * 256 + threadIdx.x;  // GNUM*512 total
    int g = i >> 9, c = i & 511;
    float v;
    if (c < 256) {
        v = pmax[g * 256 + c];
        pmax[g * 256 + c] = 0.f;
    } else {
        int cc = c - 256;
        v = psum[g * 256 + cc] / fmaxf(cnt[g], 1.f);
        psum[g * 256 + cc] = 0.f;
    }
    acc[i] += v;
    if (i < 512) stats[i] = 0.f;
}

// ---------------- fused readout MLP (fp32): [64,512]->256->128->250 ----------------
__global__ __launch_bounds__(256)
void readout_kernel(const float* __restrict__ acc,
                    const float* __restrict__ w1, const float* __restrict__ b1,
                    const float* __restrict__ w2, const float* __restrict__ b2,
                    const float* __restrict__ w3, const float* __restrict__ b3,
                    float* __restrict__ out) {
    __shared__ float a[512], z1[256], z2[128];
    int g = blockIdx.x, t = threadIdx.x;
    a[t] = acc[g * 512 + t];
    a[t + 256] = acc[g * 512 + 256 + t];
    __syncthreads();
    float s = b1[t];
    for (int k = 0; k < 512; ++k) s = fmaf(a[k], w1[k * 256 + t], s);
    z1[t] = fmaxf(s, 0.f);
    __syncthreads();
    if (t < 128) {
        float s2 = b2[t];
        for (int k = 0; k < 256; ++k) s2 = fmaf(z1[k], w2[k * 128 + t], s2);
        z2[t] = fmaxf(s2, 0.f);
    }
    __syncthreads();
    if (t < 250) {
        float s3 = b3[t];
        for (int k = 0; k < 128; ++k) s3 = fmaf(z2[k], w3[k * 250 + t], s3);
        out[g * 250 + t] = s3;
    }
}

extern "C" void kernel_launch(void* const* d_in, const int* in_sizes, int n_in,
                              void* d_out, int out_size, void* d_ws, size_t ws_size,
                              hipStream_t stream) {
    const float* x     = (const float*)d_in[0];
    const int* ei      = (const int*)d_in[1];
    const int* batch   = (const int*)d_in[2];
    const float* w1a   = (const float*)d_in[3];
    const float* b1a   = (const float*)d_in[4];
    const float* w1b   = (const float*)d_in[5];
    const float* b1b   = (const float*)d_in[6];
    const float* W_in  = (const float*)d_in[7];
    const float* b_in  = (const float*)d_in[8];
    const float* W_out = (const float*)d_in[9];
    const float* b_out = (const float*)d_in[10];
    const float* gamma = (const float*)d_in[11];
    const float* beta  = (const float*)d_in[12];
    const float* l1w   = (const float*)d_in[13];
    const float* l1b   = (const float*)d_in[14];
    const float* l2w   = (const float*)d_in[15];
    const float* l2b   = (const float*)d_in[16];
    const float* l3w   = (const float*)d_in[17];
    const float* l3b   = (const float*)d_in[18];

    const int N = in_sizes[2];
    const int E = in_sizes[1] / 2;
    const int* srcv = ei;
    const int* dstv = ei + E;

    // ---- workspace layout (~82 MB) ----
    u16* B0 = (u16*)d_ws;                       // N*256 bf16 (z / z2 in-place L>=1)
    u16* B1 = B0 + (size_t)N * 256;             // N*256 bf16 (Xb first half; L0 out)
    u16* B2 = B1 + (size_t)N * 256;             // N*256 bf16 (post-BN H)
    u16* Xb = B1;                               // N*128 bf16
    u16* Wp = B2 + (size_t)N * 256;             // 32768 + 7*65536 u16 frag-ordered weights
    float* stats = (float*)(Wp + 32768 + 7 * 65536);  // 512
    float* pmax  = stats + 512;                 // 16384
    float* psum  = pmax + GNUM * 256;           // 16384
    float* acc   = psum + GNUM * 256;           // 32768
    float* cnt   = acc + GNUM * 512;            // 64
    int* deg    = (int*)(cnt + GNUM);           // N
    int* part   = deg + N;                      // N
    int* bsum   = part + N;                     // 256
    int* offs   = bsum + 256;                   // N+1
    int* cursor = offs + N + 1;                 // N+1
    int* eidx   = cursor + N + 1;               // E

    int nb256 = (N + 255) / 256;
    int nbM   = (N + 63) / 64;
    int nbP   = (N + 15) / 16;
    int nb64  = (N + 63) / 64;
    int nbW   = (N + 3) / 4;
    int eb    = (E + 255) / 256;
    const int FTOT = 512 + GNUM * 256 * 2 + GNUM * 512 + GNUM;  // 66112

    // --- init + CSR build + per-graph counts ---
    zero_i<<<nb256, 256, 0, stream>>>(deg, N);
    zero_f<<<(FTOT + 255) / 256, 256, 0, stream>>>(stats, FTOT);
    deg_kernel<<<eb, 256, 0, stream>>>(dstv, deg, E);
    scan_block<<<nb256, 256, 0, stream>>>(deg, part, bsum, N);
    scan_bsum<<<1, 256, 0, stream>>>(bsum, nb256);
    scan_fix<<<nb256, 256, 0, stream>>>(part, bsum, offs, cursor, N);
    fill_kernel<<<eb, 256, 0, stream>>>(srcv, dstv, cursor, eidx, E);
    cnt_kernel<<<(nb64 + 255) / 256, 256, 0, stream>>>(batch, cnt, N);

    // --- x -> bf16; weights -> fragment-ordered bf16 ---
    cvt_x<<<(N * 128 / 4 + 255) / 256, 256, 0, stream>>>(x, Xb, N * 128 / 4);
    u16* Wp1 = Wp + 32768;                      // 7 K=256 matrices after the K=128 one
    transw_frag<128><<<(128 * 32 + 255) / 256, 256, 0, stream>>>(w1a, Wp);
    transw_frag<256><<<(256 * 32 + 255) / 256, 256, 0, stream>>>(w1b, Wp1);
    for (int i = 0; i < 3; ++i) {
        transw_frag<256><<<(256 * 32 + 255) / 256, 256, 0, stream>>>(
            W_in + (size_t)i * 65536, Wp1 + (size_t)(1 + i) * 65536);
        transw_frag<256><<<(256 * 32 + 255) / 256, 256, 0, stream>>>(
            W_out + (size_t)i * 65536, Wp1 + (size_t)(4 + i) * 65536);
    }

    for (int L = 0; L < 4; ++L) {
        if (L == 0) {
            agg3<128><<<nbW, 256, 0, stream>>>(Xb, offs, eidx, B0, N);
            gin_mlp<128><<<nbM, 256, 0, stream>>>(B0, Wp, b1a, Wp1, b1b, B1, stats, N);
            bn_pool<<<nbP, 256, 0, stream>>>(B1, stats, gamma, beta,
                                             batch, B2, pmax, psum, N);
        } else {
            agg3<256><<<nbW, 256, 0, stream>>>(B2, offs, eidx, B0, N);
            gin_mlp<256><<<nbM, 256, 0, stream>>>(
                B0, Wp1 + (size_t)(1 + L - 1) * 65536, b_in + (L - 1) * 256,
                Wp1 + (size_t)(4 + L - 1) * 65536, b_out + (L - 1) * 256, B0, stats, N);
            bn_pool<<<nbP, 256, 0, stream>>>(B0, stats, gamma + L * 256, beta + L * 256,
                                             batch, B2, pmax, psum, N);
        }
        acc_update<<<(GNUM * 512) / 256, 256, 0, stream>>>(pmax, psum, cnt, acc, stats);
    }
    readout_kernel<<<GNUM, 256, 0, stream>>>(acc, l1w, l1b, l2w, l2b, l3w, l3b,
                                             (float*)d_out);
}